// Round 2
// baseline (174.769 us; speedup 1.0000x reference)
//
#include <hip/hip_runtime.h>
#include <hip/hip_bf16.h>

#define N_TOKENS 8192
#define IN_FEAT 1024
#define OUT_FEAT 1024
#define NUM_EXPERT 8

#define BM 128
#define BN 128
#define BK 32
#define LDSW 20  // dwords per LDS row: 16 data + 4 pad (2-way bank alias = free)

typedef __bf16 bf16x8 __attribute__((ext_vector_type(8)));
typedef float f32x4 __attribute__((ext_vector_type(4)));

// fp32 -> bf16 round-to-nearest-even, two packed into one dword.
__device__ __forceinline__ unsigned int rne16(float x) {
    union { float f; unsigned int u; } c;
    c.f = x;
    unsigned int u = c.u;
    u += 0x7fffu + ((u >> 16) & 1u);
    return u >> 16;
}
__device__ __forceinline__ unsigned int pk2(float x, float y) {
    return rne16(x) | (rne16(y) << 16);
}

// Single-block counting sort of token indices by expert.
// perm[8192]: token ids grouped by expert; seg[9]: segment offsets.
__global__ __launch_bounds__(1024) void moe_sort(const int* __restrict__ gate,
                                                 int* __restrict__ perm,
                                                 int* __restrict__ seg) {
    __shared__ int cnt[NUM_EXPERT];
    __shared__ int cur[NUM_EXPERT];
    const int t = threadIdx.x;
    const int lane = t & 63;
    const unsigned long long lt = (lane == 0) ? 0ull : (~0ull >> (64 - lane));

    if (t < NUM_EXPERT) cnt[t] = 0;
    __syncthreads();

    for (int i = t; i < N_TOKENS; i += 1024) {
        int g = gate[i];
        #pragma unroll
        for (int e = 0; e < NUM_EXPERT; ++e) {
            unsigned long long m = __ballot(g == e);
            if (g == e && (m & lt) == 0ull) {
                atomicAdd(&cnt[e], __popcll(m));
            }
        }
    }
    __syncthreads();

    if (t == 0) {
        int s = 0;
        #pragma unroll
        for (int e = 0; e < NUM_EXPERT; ++e) { cur[e] = s; seg[e] = s; s += cnt[e]; }
        seg[NUM_EXPERT] = s;
    }
    __syncthreads();

    for (int i = t; i < N_TOKENS; i += 1024) {
        int g = gate[i];
        #pragma unroll
        for (int e = 0; e < NUM_EXPERT; ++e) {
            unsigned long long m = __ballot(g == e);
            if (g == e) {
                int rank = __popcll(m & lt);
                int leader = (int)__ffsll((unsigned long long)m) - 1;
                int p0 = 0;
                if (rank == 0) p0 = atomicAdd(&cur[e], __popcll(m));
                p0 = __shfl(p0, leader);
                perm[p0 + rank] = i;
            }
        }
    }
}

// Grouped GEMM: block = (expert e, mtile, ntile). Gathers 128 token rows via
// perm, converts fp32->bf16 into LDS, 16x16x32 bf16 MFMA, scatters fp32 out.
__global__ __launch_bounds__(256, 2) void moe_gemm(
    const float* __restrict__ inp,
    const float* __restrict__ weight,
    const int* __restrict__ perm,
    const int* __restrict__ seg,
    float* __restrict__ out) {

    const int bid = blockIdx.x;
    const int e = bid >> 9;          // 64 mtiles * 8 ntiles = 512 blocks/expert
    const int rem = bid & 511;
    const int mtile = rem >> 3;
    const int ntile = rem & 7;

    const int base = seg[e];
    const int cnt = seg[e + 1] - base;
    if (mtile * BM >= cnt) return;

    __shared__ unsigned int lA[BM * LDSW];
    __shared__ unsigned int lB[BN * LDSW];
    __shared__ int rowids[BM];

    const int t = threadIdx.x;
    if (t < BM) {
        int r = mtile * BM + t;
        rowids[t] = (r < cnt) ? perm[base + r] : -1;
    }
    __syncthreads();

    // staging: thread t stages row (t>>1), 16-float column half ((t&1)*16)
    const int srow = t >> 1;
    const int scol = (t & 1) << 4;
    const int tokA = rowids[srow];
    const bool aval = (tokA >= 0);
    const float* aptr = inp + (aval ? tokA : 0) * IN_FEAT + scol;
    const float* bptr = weight + e * (OUT_FEAT * IN_FEAT)
                        + (ntile * BN + srow) * IN_FEAT + scol;
    const int sdst = srow * LDSW + (scol >> 1);

    const int wave = t >> 6;
    const int lane = t & 63;
    const int wm = (wave & 1) << 6;   // 2x2 wave grid over 128x128
    const int wn = (wave >> 1) << 6;
    const int l15 = lane & 15;
    const int quad = lane >> 4;

    f32x4 acc[4][4];
    #pragma unroll
    for (int i = 0; i < 4; ++i)
        #pragma unroll
        for (int j = 0; j < 4; ++j)
            acc[i][j] = (f32x4)0.0f;

    // prologue: prefetch k0=0 slab into registers
    float4 ra[4], rb[4];
    {
        const float4* ap = (const float4*)aptr;
        const float4* bp = (const float4*)bptr;
        #pragma unroll
        for (int i = 0; i < 4; ++i) { ra[i] = ap[i]; rb[i] = bp[i]; }
    }

    for (int k0 = 0; k0 < IN_FEAT; k0 += BK) {
        // convert current slab to packed bf16
        unsigned int ua[8], ub[8];
        #pragma unroll
        for (int i = 0; i < 4; ++i) {
            ua[2 * i]     = pk2(ra[i].x, ra[i].y);
            ua[2 * i + 1] = pk2(ra[i].z, ra[i].w);
            ub[2 * i]     = pk2(rb[i].x, rb[i].y);
            ub[2 * i + 1] = pk2(rb[i].z, rb[i].w);
        }
        if (!aval) {
            #pragma unroll
            for (int i = 0; i < 8; ++i) ua[i] = 0u;
        }

        __syncthreads();  // previous iteration's LDS reads complete
        *(uint4*)&lA[sdst]     = make_uint4(ua[0], ua[1], ua[2], ua[3]);
        *(uint4*)&lA[sdst + 4] = make_uint4(ua[4], ua[5], ua[6], ua[7]);
        *(uint4*)&lB[sdst]     = make_uint4(ub[0], ub[1], ub[2], ub[3]);
        *(uint4*)&lB[sdst + 4] = make_uint4(ub[4], ub[5], ub[6], ub[7]);
        __syncthreads();

        // prefetch next slab while computing this one
        if (k0 + BK < IN_FEAT) {
            const float4* ap = (const float4*)(aptr + k0 + BK);
            const float4* bp = (const float4*)(bptr + k0 + BK);
            #pragma unroll
            for (int i = 0; i < 4; ++i) { ra[i] = ap[i]; rb[i] = bp[i]; }
        }

        // fragments: A[m=l15][k=quad*8+j], B[k=quad*8+j][n=l15]
        bf16x8 af[4], bq[4];
        #pragma unroll
        for (int i = 0; i < 4; ++i)
            af[i] = *(const bf16x8*)&lA[(wm + i * 16 + l15) * LDSW + (quad << 2)];
        #pragma unroll
        for (int i = 0; i < 4; ++i)
            bq[i] = *(const bf16x8*)&lB[(wn + i * 16 + l15) * LDSW + (quad << 2)];

        #pragma unroll
        for (int i = 0; i < 4; ++i)
            #pragma unroll
            for (int j = 0; j < 4; ++j)
                acc[i][j] = __builtin_amdgcn_mfma_f32_16x16x32_bf16(
                    af[i], bq[j], acc[i][j], 0, 0, 0);
    }

    // epilogue: C/D layout col=lane&15, row=quad*4+reg (verified m89)
    #pragma unroll
    for (int mi = 0; mi < 4; ++mi) {
        #pragma unroll
        for (int r = 0; r < 4; ++r) {
            int row = wm + mi * 16 + quad * 4 + r;
            int token = rowids[row];
            if (token >= 0) {
                float* op = out + token * OUT_FEAT + ntile * BN + wn;
                #pragma unroll
                for (int ni = 0; ni < 4; ++ni)
                    op[ni * 16 + l15] = acc[mi][ni][r];
            }
        }
    }
}

extern "C" void kernel_launch(void* const* d_in, const int* in_sizes, int n_in,
                              void* d_out, int out_size, void* d_ws, size_t ws_size,
                              hipStream_t stream) {
    const float* inp = (const float*)d_in[0];
    const int* gate = (const int*)d_in[1];
    const float* weight = (const float*)d_in[2];
    float* out = (float*)d_out;

    int* perm = (int*)d_ws;           // 8192 ints
    int* seg = perm + N_TOKENS;       // 9 ints

    moe_sort<<<1, 1024, 0, stream>>>(gate, perm, seg);

    const int grid = NUM_EXPERT * (N_TOKENS / BM) * (OUT_FEAT / BN);  // 4096
    moe_gemm<<<grid, 256, 0, stream>>>(inp, weight, perm, seg, out);
}